// Round 1
// baseline (315.942 us; speedup 1.0000x reference)
//
#include <hip/hip_runtime.h>
#include <hip/hip_bf16.h>

// SiLU-and-mul: x shape (4, 2048, 32768) fp32; gate = x[..., :16384],
// up = x[..., 16384:]; out = silu(gate) * up, shape (4, 2048, 16384) fp32.
// Memory-bound: 1 GiB read + 0.5 GiB write -> ~255 us at 6.3 TB/s.

#define D_HALF   16384            // half of last dim (floats)
#define D4_HALF  (D_HALF / 4)     // 4096 float4 per half-row
#define D4_FULL  (D4_HALF * 2)    // 8192 float4 per input row

__device__ __forceinline__ float silu(float x) {
    // x * sigmoid(x) = x / (1 + e^-x). Large -x: expf -> inf -> 0. Safe.
    return x / (1.0f + expf(-x));
}

__global__ void SiluAndMul_kernel(const float4* __restrict__ x,
                                  float4* __restrict__ out,
                                  long long n4) {
    long long i = (long long)blockIdx.x * blockDim.x + threadIdx.x;
    const long long stride = (long long)gridDim.x * blockDim.x;
    for (; i < n4; i += stride) {
        long long row = i >> 12;           // i / D4_HALF
        long long col = i & (D4_HALF - 1); // i % D4_HALF
        long long g_idx = row * D4_FULL + col;
        float4 g = x[g_idx];
        float4 u = x[g_idx + D4_HALF];
        float4 r;
        r.x = silu(g.x) * u.x;
        r.y = silu(g.y) * u.y;
        r.z = silu(g.z) * u.z;
        r.w = silu(g.w) * u.w;
        out[i] = r;
    }
}

extern "C" void kernel_launch(void* const* d_in, const int* in_sizes, int n_in,
                              void* d_out, int out_size, void* d_ws, size_t ws_size,
                              hipStream_t stream) {
    const float4* x = (const float4*)d_in[0];
    float4* out = (float4*)d_out;
    long long n4 = (long long)out_size / 4;   // 33,554,432 float4 outputs

    const int block = 256;
    // ~8 blocks/CU on 256 CUs; grid-stride covers the rest (64 iters/thread).
    int grid = 2048;
    long long need = (n4 + block - 1) / block;
    if (need < grid) grid = (int)need;

    SiluAndMul_kernel<<<grid, block, 0, stream>>>(x, out, n4);
}